// Round 11
// baseline (280.576 us; speedup 1.0000x reference)
//
#include <hip/hip_runtime.h>
#include <hip/hip_bf16.h>

typedef __hip_bfloat16 bf16;
typedef short bf16x8 __attribute__((ext_vector_type(8)));   // 8 bf16 = 4 VGPRs (MFMA frag)
typedef float f32x4 __attribute__((ext_vector_type(4)));
typedef short s4 __attribute__((ext_vector_type(4)));

#define LL 2048
#define SS 2048
#define EE 1024
#define HH 16
#define HD 64
#define MM (LL * 2)   // 4096 rows (l*B+b)

static __device__ __forceinline__ short f2bs(float f) {
  bf16 h = __float2bfloat16(f);
  short u;
  __builtin_memcpy(&u, &h, 2);
  return u;
}

// pack 8 f32 -> bf16x8 and store to LDS (one ds_write_b128)
static __device__ __forceinline__ void st8(bf16* p, float4 x, float4 y) {
  bf16x8 v;
  v[0] = f2bs(x.x); v[1] = f2bs(x.y); v[2] = f2bs(x.z); v[3] = f2bs(x.w);
  v[4] = f2bs(y.x); v[5] = f2bs(y.y); v[6] = f2bs(y.z); v[7] = f2bs(y.w);
  *(bf16x8*)p = v;
}

// async global->LDS, 16B per lane. LDS dest must be wave-uniform base + lane*16.
#define GLL16(gp, lp) __builtin_amdgcn_global_load_lds(                        \
    (const __attribute__((address_space(1))) void*)(gp),                       \
    (__attribute__((address_space(3))) void*)(lp), 16, 0, 0)

// ---------------------------------------------------------------------------
// ROUND-11 fused QKV — round-7/10 proven structure (128m x 64n, BK=32, grid
// 1536 = 6/CU, packed zero-conflict LDS), with TWO launch-elimination changes:
//  (1) B reg-staged DIRECTLY from f32 W (same T14 reg->st8 path and packed-
//      layout formula as A; write pattern is the measured-0-conflict one) —
//      removes the weight-cvt prep pass entirely.
//  (2) RoPE cos/sin computed INLINE in the epilogue with the bit-identical
//      expression the old table used (sincosf(pos * expf(-fi*ln(1e4)/32)))
//      — 4 expf + 16 sincosf per thread, only 8 cs values live at a time.
// Rationale: accounting across rounds 7-10 shows ~40-50 us of the 249 total
// is launch/prep overhead (5 launches x ~10 us); qkv itself is structure-
// capped at ~340 TF (byte- and schedule-invariant over 6 rounds), so we
// trade ~3 us of in-kernel work to delete 2 launches + ~10 us of prep.
__global__ __launch_bounds__(256, 6) void qkv_kernel(
    const float* __restrict__ Xq, const float* __restrict__ Xk,
    const float* __restrict__ Xv,
    const float* __restrict__ Wq, const float* __restrict__ Wk,
    const float* __restrict__ Wv,
    const float* __restrict__ bq, const float* __restrict__ bk,
    const float* __restrict__ bv, bf16* __restrict__ Qr,
    bf16* __restrict__ Kr, bf16* __restrict__ Vt)
{
  __shared__ __align__(16) bf16 As[2][4096];   // 128 rows -> 64 lrows x 64 = 8 KB/buf
  __shared__ __align__(16) bf16 Bs[2][2048];   // 64 rows -> 32 lrows x 64 = 4 KB/buf

  const int tid = threadIdx.x;
  const int w = tid >> 6;
  const int lane = tid & 63;
  const int l15 = lane & 15, quad = lane >> 4;
  const int id = blockIdx.x;
  const int z = id >> 9;                 // 0=Q 1=K 2=V
  const int g = id & 511;
  const int tmb = (g & 31) * 128;        // same-A blocks (n varies) land on same XCD
  const int tn  = (g >> 5) * 64;

  const float* Xf = (z == 0) ? Xq : (z == 1) ? Xk : Xv;
  const float* Wf = (z == 0) ? Wq : (z == 1) ? Wk : Wv;
  const float* bias = (z == 0) ? bq : (z == 1) ? bk : bv;
  bf16* dst = (z == 0) ? Qr : (z == 1) ? Kr : Vt;

  // A staging: thread t covers rows ar and ar+64, k-chunk akc (8 f32).
  const int ar = tid >> 2;               // 0..63
  const int akc = tid & 3;
  const float* gA0 = Xf + (size_t)(tmb + ar) * EE + akc * 8;
  const float* gA1 = gA0 + (size_t)64 * EE;
  const int aw0 = (ar >> 1) * 64 + (((((ar & 1) << 2) | akc) ^ ((ar >> 1) & 7)) * 8);
  const int aw1 = aw0 + 2048;            // row+64 -> lrow+32, same &7 -> same slot

  // B staging (f32 W, reg-stage + st8): thread t covers B-row ar (0..63),
  // chunk akc — identical packed-slot formula as A (measured 0-conflict).
  const float* gB = Wf + (size_t)(tn + ar) * EE + akc * 8;
  const int bw0 = aw0;                   // same (row, chunk) -> same slot math

  // fragment read base (A and B share the formula): row = 16*base + l15, kc = quad
  const int arbase = (l15 >> 1) * 64 + (((((l15 & 1) << 2) | quad) ^ (l15 >> 1)) * 8);

  f32x4 zero4 = {0.f, 0.f, 0.f, 0.f};
  f32x4 acc[2][4];
#pragma unroll
  for (int mi = 0; mi < 2; ++mi)
#pragma unroll
    for (int ni = 0; ni < 4; ++ni) acc[mi][ni] = zero4;

  {  // prologue: stage tile 0 (A and B both reg-staged)
    float4 a00 = *(const float4*)(gA0);
    float4 a01 = *(const float4*)(gA0 + 4);
    float4 a10 = *(const float4*)(gA1);
    float4 a11 = *(const float4*)(gA1 + 4);
    float4 b00 = *(const float4*)(gB);
    float4 b01 = *(const float4*)(gB + 4);
    st8(&As[0][aw0], a00, a01);
    st8(&As[0][aw1], a10, a11);
    st8(&Bs[0][bw0], b00, b01);
  }
  __syncthreads();

  for (int t = 0; t < 32; ++t) {
    const int cur = t & 1;
    float4 a00, a01, a10, a11, b00, b01;
    if (t < 31) {                        // issue next-tile loads EARLY (T14)
      const int k0 = (t + 1) * 32;
      a00 = *(const float4*)(gA0 + k0);
      a01 = *(const float4*)(gA0 + k0 + 4);
      a10 = *(const float4*)(gA1 + k0);
      a11 = *(const float4*)(gA1 + k0 + 4);
      b00 = *(const float4*)(gB + k0);
      b01 = *(const float4*)(gB + k0 + 4);
    }
    // compute current tile: 8 MFMA/wave (wave = 32m x 64n)
    bf16x8 af0 = *(const bf16x8*)(&As[cur][w * 1024 + arbase]);
    bf16x8 af1 = *(const bf16x8*)(&As[cur][w * 1024 + 512 + arbase]);
#pragma unroll
    for (int ni = 0; ni < 4; ++ni) {
      bf16x8 bfr = *(const bf16x8*)(&Bs[cur][ni * 512 + arbase]);
      acc[0][ni] = __builtin_amdgcn_mfma_f32_16x16x32_bf16(af0, bfr, acc[0][ni], 0, 0, 0);
      acc[1][ni] = __builtin_amdgcn_mfma_f32_16x16x32_bf16(af1, bfr, acc[1][ni], 0, 0, 0);
    }
    if (t < 31) {                        // write-late: cvt lands after compute
      st8(&As[cur ^ 1][aw0], a00, a01);
      st8(&As[cur ^ 1][aw1], a10, a11);
      st8(&Bs[cur ^ 1][bw0], b00, b01);
    }
    __syncthreads();                     // drains ds_writes + reads
  }

  float bz[4];
#pragma unroll
  for (int ni = 0; ni < 4; ++ni) bz[ni] = bias[tn + ni * 16 + l15];

  if (z <= 1) {                          // RoPE epilogue (Q, K), inline cs
    const int B0h = (tmb + w * 32 + quad * 4) >> 1;   // even base, exact
#pragma unroll
    for (int ni = 0; ni < 4; ++ni) {
      const int n = tn + ni * 16 + l15;
      const int fi = (ni * 16 + l15) >> 1;            // == (n&63)>>1
      // bit-identical to the old table: freq = 10000^(-fi/32)
      float freq = expf(-(float)fi * (9.210340371976184f / 32.0f));
      float cc[4], sn[4];                             // pos idx = mi*2 + (r>>1)
#pragma unroll
      for (int pp = 0; pp < 4; ++pp) {
        int pos = B0h + (pp >> 1) * 8 + (pp & 1);     // (m>>1) for (mi=pp>>1, rh=pp&1)
        sincosf((float)pos * freq, &sn[pp], &cc[pp]);
      }
#pragma unroll
      for (int mi = 0; mi < 2; ++mi) {
#pragma unroll
        for (int r = 0; r < 4; ++r) {
          const int m = tmb + w * 32 + mi * 16 + quad * 4 + r;
          float v = acc[mi][ni][r] + bz[ni];
          float other = __shfl_xor(v, 1, 64);   // pair element (n^1) is in lane^1
          const int pi = mi * 2 + (r >> 1);
          int pos = m >> 1, b = m & 1, d = n & 63, h = n >> 6;
          (void)pos;
          float rv = (d & 1) ? (other * sn[pi] + v * cc[pi])
                             : (v * cc[pi] - other * sn[pi]);
          dst[((size_t)(b * HH + h) * LL + (m >> 1)) * HD + d] = __float2bfloat16(rv);
        }
      }
    }
  } else {                               // V: store transposed [b][h][d][pos]
#pragma unroll
    for (int mi = 0; mi < 2; ++mi) {
#pragma unroll
      for (int ni = 0; ni < 4; ++ni) {
        const int n = tn + ni * 16 + l15;
#pragma unroll
        for (int r = 0; r < 4; ++r) {
          const int m = tmb + w * 32 + mi * 16 + quad * 4 + r;
          float v = acc[mi][ni][r] + bz[ni];
          int pos = m >> 1, b = m & 1, d = n & 63, h = n >> 6;
          dst[((size_t)(b * HH + h) * HD + d) * SS + pos] = __float2bfloat16(v);
        }
      }
    }
  }
}

// ---------------------------------------------------------------------------
// ROUND-11 O-projection: round-10 geometry (64m x 64n, BK=64, grid (64,16) =
// 1024 = 4/CU, 128-B rows + (row&7) XOR swizzle) with W reg-staged from f32
// (removes the Wb dependency; write slots match the read swizzle exactly and
// are balanced <=8 lanes per 4-bank group = the measured-0-conflict pattern).
__global__ __launch_bounds__(256, 4) void projo_kernel(
    const bf16* __restrict__ X, const float* __restrict__ W,
    const float* __restrict__ bias, float* __restrict__ dst)
{
  __shared__ __align__(16) bf16 As[2][64 * 64];    // 8 KB/buf (ctx via gll)
  __shared__ __align__(16) bf16 Bs[2][64 * 64];    // 8 KB/buf (W reg-staged)

  const int tid = threadIdx.x;
  const int w = tid >> 6;
  const int lane = tid & 63;
  const int l15 = lane & 15, quad = lane >> 4;
  const int tmb = blockIdx.x * 64;
  const int tn  = blockIdx.y * 64;

  // A staging (gll): wave w covers rows w*16..w*16+15 as 2 glls (8 rows,
  // 8 chunks each); source chunk pre-swizzled: c_global = (lane&7) ^ srow.
  const int srow = lane >> 3;                 // 0..7 == row&7 for every gll
  const int gswz = ((lane & 7) ^ srow) * 8;
  const bf16* gA0 = X + (size_t)(tmb + w * 16 + srow) * EE + gswz;
  const bf16* gA1 = gA0 + (size_t)8 * EE;

  // W staging (f32 reg-stage): thread t covers row wr = t>>2 (0..63),
  // chunks wc and wc+4 (8 f32 each). LDS slot = chunk ^ (row&7).
  const int wr = tid >> 2;
  const int wc = tid & 3;
  const float* gW0 = W + (size_t)(tn + wr) * EE + wc * 8;
  const float* gW1 = gW0 + 32;                // chunk wc+4
  const int bw0 = wr * 64 + ((wc       ^ (wr & 7)) * 8);
  const int bw1 = wr * 64 + (((wc | 4) ^ (wr & 7)) * 8);

  // read-side swizzled chunk offsets (row&7 == l15&7 for all frag reads)
  const int ksw0 = ((quad    ) ^ (l15 & 7)) * 8;   // k-half 0 (k 0..31)
  const int ksw1 = ((quad + 4) ^ (l15 & 7)) * 8;   // k-half 1 (k 32..63)

  f32x4 zero4 = {0.f, 0.f, 0.f, 0.f};
  f32x4 acc[4];
#pragma unroll
  for (int ni = 0; ni < 4; ++ni) acc[ni] = zero4;

  {  // prologue: stage K-tile 0
    GLL16(gA0, (bf16*)&As[0][(w * 16) * 64] + lane * 8);
    GLL16(gA1, (bf16*)&As[0][(w * 16 + 8) * 64] + lane * 8);
    float4 w00 = *(const float4*)(gW0);
    float4 w01 = *(const float4*)(gW0 + 4);
    float4 w10 = *(const float4*)(gW1);
    float4 w11 = *(const float4*)(gW1 + 4);
    st8(&Bs[0][bw0], w00, w01);
    st8(&Bs[0][bw1], w10, w11);
  }
  __syncthreads();

  for (int t = 0; t < 16; ++t) {
    const int cur = t & 1;
    float4 w00, w01, w10, w11;
    if (t < 15) {                        // issue next-tile loads EARLY (T14)
      const int k0 = (t + 1) * 64;
      GLL16(gA0 + k0, (bf16*)&As[cur ^ 1][(w * 16) * 64] + lane * 8);
      GLL16(gA1 + k0, (bf16*)&As[cur ^ 1][(w * 16 + 8) * 64] + lane * 8);
      w00 = *(const float4*)(gW0 + k0);
      w01 = *(const float4*)(gW0 + k0 + 4);
      w10 = *(const float4*)(gW1 + k0);
      w11 = *(const float4*)(gW1 + k0 + 4);
    }
    // 8 MFMA/wave: 2 k-halves x 4 n-frags; wave = 16m x 64n
    bf16x8 a0 = *(const bf16x8*)(&As[cur][(w * 16 + l15) * 64 + ksw0]);
    bf16x8 a1 = *(const bf16x8*)(&As[cur][(w * 16 + l15) * 64 + ksw1]);
#pragma unroll
    for (int ni = 0; ni < 4; ++ni) {
      bf16x8 b0 = *(const bf16x8*)(&Bs[cur][(ni * 16 + l15) * 64 + ksw0]);
      bf16x8 b1 = *(const bf16x8*)(&Bs[cur][(ni * 16 + l15) * 64 + ksw1]);
      acc[ni] = __builtin_amdgcn_mfma_f32_16x16x32_bf16(a0, b0, acc[ni], 0, 0, 0);
      acc[ni] = __builtin_amdgcn_mfma_f32_16x16x32_bf16(a1, b1, acc[ni], 0, 0, 0);
    }
    if (t < 15) {                        // write-late
      st8(&Bs[cur ^ 1][bw0], w00, w01);
      st8(&Bs[cur ^ 1][bw1], w10, w11);
    }
    __syncthreads();
  }

  float bz[4];
#pragma unroll
  for (int ni = 0; ni < 4; ++ni) bz[ni] = bias[tn + ni * 16 + l15];

#pragma unroll
  for (int ni = 0; ni < 4; ++ni) {
    const int n = tn + ni * 16 + l15;
#pragma unroll
    for (int r = 0; r < 4; ++r) {
      const int m = tmb + w * 16 + quad * 4 + r;
      dst[(size_t)m * EE + n] = acc[ni][r] + bz[ni];
    }
  }
}

// ---------------------------------------------------------------------------
// Flash attention — round-7/10 16q/wave version; ROUND-11 change: mask bias
// computed inline from the uchar mask (uchar4 load + select, replacing the
// prep-computed float maskf 1:1).
__global__ __launch_bounds__(256, 4) void attn_kernel(
    const bf16* __restrict__ Qr, const bf16* __restrict__ Kr,
    const bf16* __restrict__ Vt, const unsigned char* __restrict__ maskb,
    bf16* __restrict__ ctx)
{
  __shared__ __align__(16) bf16 Ks[2][64 * 64];       // 16 KB: [buf][s][d]
  __shared__ __align__(16) bf16 Vs[2][64 * 64];       // 16 KB: [buf][d][s]
  __shared__ __align__(16) short Plds[4][16][56];     // 7 KB: [wave][q][s str 56]

  const int w = threadIdx.x >> 6;
  const int lane = threadIdx.x & 63;
  const int l15 = lane & 15, quad = lane >> 4;
  const int id = blockIdx.x;
  const int bh = id & 31;             // XCD = bh % 8
  const int qt = id >> 5;             // 0..31
  const int b = bh >> 4, h = bh & 15;
  const int q0 = qt * 64 + w * 16;

  const bf16* Qbh = Qr + (size_t)bh * LL * HD;
  const bf16* Kbh = Kr + (size_t)bh * SS * HD;
  const bf16* Vbh = Vt + (size_t)bh * HD * SS;
  const unsigned char* mrow = maskb + b * SS;

  bf16x8 qf0, qf1;
  {
    const bf16* qp = Qbh + (size_t)(q0 + l15) * HD + quad * 8;
    qf0 = *(const bf16x8*)(qp);
    qf1 = *(const bf16x8*)(qp + 32);
  }

  const int srow = lane >> 3;                     // 0..7
  const int gswz = ((lane & 7) ^ srow) * 8;       // source chunk, elems
  const int kswz0 = ((quad    ) ^ (l15 & 7)) * 8;
  const int kswz1 = ((quad + 4) ^ (l15 & 7)) * 8;

#define STAGE(buf, S0) {                                                       \
    _Pragma("unroll")                                                          \
    for (int i = 0; i < 2; ++i) {                                              \
      const int rb = w * 16 + i * 8;                                           \
      GLL16(Kbh + (size_t)((S0) + rb + srow) * HD + gswz,                      \
            (bf16*)&Ks[buf][rb * 64] + lane * 8);                              \
      GLL16(Vbh + (size_t)(rb + srow) * SS + (S0) + gswz,                      \
            (bf16*)&Vs[buf][rb * 64] + lane * 8);                              \
    }                                                                          \
  }

  f32x4 zero4 = {0.f, 0.f, 0.f, 0.f};
  f32x4 o[4];
#pragma unroll
  for (int t = 0; t < 4; ++t) o[t] = zero4;
  float ps = 0.f;

  STAGE(0, 0);
  __syncthreads();

  for (int t = 0; t < SS / 64; ++t) {
    const int s0 = t * 64;
    const int cur = t & 1;
    if (t + 1 < SS / 64) STAGE(cur ^ 1, s0 + 64);   // prefetch next 64-s tile

#pragma unroll
    for (int ss = 0; ss < 2; ++ss) {
      const bf16* Kb = &Ks[cur][ss * 32 * 64];
      bf16x8 kf00 = *(const bf16x8*)(Kb + (l15)      * 64 + kswz0);
      bf16x8 kf01 = *(const bf16x8*)(Kb + (l15)      * 64 + kswz1);
      bf16x8 kf10 = *(const bf16x8*)(Kb + (16 + l15) * 64 + kswz0);
      bf16x8 kf11 = *(const bf16x8*)(Kb + (16 + l15) * 64 + kswz1);
      bf16x8 vf[4];
#pragma unroll
      for (int tt = 0; tt < 4; ++tt)
        vf[tt] = *(const bf16x8*)(&Vs[cur][0] + (tt * 16 + l15) * 64 +
                                  (((ss * 4 + quad) ^ (l15 & 7)) * 8));
      uchar4 u0 = *(const uchar4*)(mrow + s0 + ss * 32 + quad * 4);
      uchar4 u1 = *(const uchar4*)(mrow + s0 + ss * 32 + 16 + quad * 4);
      f32x4 mv0, mv1;
      mv0[0] = u0.x ? -1e30f : 0.f; mv0[1] = u0.y ? -1e30f : 0.f;
      mv0[2] = u0.z ? -1e30f : 0.f; mv0[3] = u0.w ? -1e30f : 0.f;
      mv1[0] = u1.x ? -1e30f : 0.f; mv1[1] = u1.y ? -1e30f : 0.f;
      mv1[2] = u1.z ? -1e30f : 0.f; mv1[3] = u1.w ? -1e30f : 0.f;

      // S^T = K.Q^T: C row = s_local (quad*4+r), C col = q_local (l15)
      f32x4 sc0 = zero4, sc1 = zero4;
      sc0 = __builtin_amdgcn_mfma_f32_16x16x32_bf16(kf00, qf0, sc0, 0, 0, 0);
      sc0 = __builtin_amdgcn_mfma_f32_16x16x32_bf16(kf01, qf1, sc0, 0, 0, 0);
      sc1 = __builtin_amdgcn_mfma_f32_16x16x32_bf16(kf10, qf0, sc1, 0, 0, 0);
      sc1 = __builtin_amdgcn_mfma_f32_16x16x32_bf16(kf11, qf1, sc1, 0, 0, 0);
      s4 pk0, pk1;
#pragma unroll
      for (int r = 0; r < 4; ++r) {
        float p = __expf(sc0[r] * 0.125f + mv0[r]);
        ps += p; pk0[r] = f2bs(p);
      }
#pragma unroll
      for (int r = 0; r < 4; ++r) {
        float p = __expf(sc1[r] * 0.125f + mv1[r]);
        ps += p; pk1[r] = f2bs(p);
      }
      *(s4*)&Plds[w][l15][quad * 4] = pk0;
      *(s4*)&Plds[w][l15][16 + quad * 4] = pk1;
      asm volatile("" ::: "memory");   // all P-writes before cross-lane P-read
      bf16x8 pf = *(const bf16x8*)&Plds[w][l15][quad * 8];
#pragma unroll
      for (int tt = 0; tt < 4; ++tt)
        o[tt] = __builtin_amdgcn_mfma_f32_16x16x32_bf16(pf, vf[tt], o[tt], 0, 0, 0);
      asm volatile("" ::: "memory");   // P-reads done before next subtile overwrites
    }
    __syncthreads();   // drains gll (next buf ready) + all waves done with cur
  }
#undef STAGE

  // softmax denominator: lane holds partial for q-col l15, s rows quad*4+r
  float lv = ps;
  lv += __shfl_xor(lv, 16, 64);
  lv += __shfl_xor(lv, 32, 64);

#pragma unroll
  for (int r = 0; r < 4; ++r) {
    float li = __shfl(lv, quad * 4 + r, 64);   // denom for q-row quad*4+r
    float inv = 1.0f / li;
    int q = q0 + quad * 4 + r;
#pragma unroll
    for (int t = 0; t < 4; ++t) {
      float val = o[t][r] * inv;
      ctx[(size_t)(q * 2 + b) * EE + (size_t)h * 64 + t * 16 + l15] = __float2bfloat16(val);
    }
  }
}

extern "C" void kernel_launch(void* const* d_in, const int* in_sizes, int n_in,
                              void* d_out, int out_size, void* d_ws, size_t ws_size,
                              hipStream_t stream) {
  const float* query = (const float*)d_in[0];
  const float* key   = (const float*)d_in[1];
  const float* value = (const float*)d_in[2];
  const unsigned char* mask = (const unsigned char*)d_in[3];
  const float* Wq = (const float*)d_in[4];
  const float* bq = (const float*)d_in[5];
  const float* Wk = (const float*)d_in[6];
  const float* bk = (const float*)d_in[7];
  const float* Wv = (const float*)d_in[8];
  const float* bv = (const float*)d_in[9];
  const float* Wo = (const float*)d_in[10];
  const float* bo = (const float*)d_in[11];

  char* ws = (char*)d_ws;
  (void)ws_size; (void)in_sizes; (void)n_in; (void)out_size;

  // Workspace (32 MB, fits every harness ws): Qr@0 | Kr@8M | Vt@16M | ctx@24M
  bf16* Qr  = (bf16*)ws;                                // [b][h][l][d]
  bf16* Kr  = (bf16*)(ws + ((size_t)8 << 20));          // [b][h][s][d]
  bf16* Vt  = (bf16*)(ws + ((size_t)16 << 20));         // [b][h][d][s]
  bf16* ctx = (bf16*)(ws + ((size_t)24 << 20));

  // 3 launches total (was 5): prep eliminated (weights reg-staged from f32,
  // RoPE table inlined in qkv epilogue, mask inlined in attn).
  qkv_kernel<<<1536, 256, 0, stream>>>(query, key, value, Wq, Wk, Wv,
                                       bq, bk, bv, Qr, Kr, Vt);

  attn_kernel<<<(LL / 64) * 2 * HH, 256, 0, stream>>>(Qr, Kr, Vt, mask, ctx);

  dim3 go(MM / 64, EE / 64);
  projo_kernel<<<go, 256, 0, stream>>>(ctx, Wo, bo, (float*)d_out);
}